// Round 12
// baseline (118.560 us; speedup 1.0000x reference)
//
#include <hip/hip_runtime.h>
#include <hip/hip_bf16.h>

#define Bq 4
#define Nn 512
#define Dd 512
#define Hh 8
#define DKk 64

typedef __bf16 bf16x8 __attribute__((ext_vector_type(8)));
typedef float f32x4 __attribute__((ext_vector_type(4)));
typedef unsigned short u16x8 __attribute__((ext_vector_type(8)));

// fp32 -> bf16 RNE (no NaN inputs here)
static __device__ __forceinline__ unsigned short f2bf(float f) {
    unsigned int u = __float_as_uint(f);
    return (unsigned short)((u + 0x7FFFu + ((u >> 16) & 1u)) >> 16);
}
static __device__ __forceinline__ unsigned short f2h(float f) {
    union { _Float16 h; unsigned short u; } cv;
    cv.h = (_Float16)f;
    return cv.u;
}
static __device__ __forceinline__ float h2f(unsigned short us) {
    union { _Float16 h; unsigned short u; } cv;
    cv.u = us;
    return (float)cv.h;
}

// ---------------------------------------------------------------------------
// Merged kernel: geo (4096 blocks) + QKV GEMM (768 blocks), striped 16:3 per
// 19-block group. EXACT round-5 structure (session-best 76.9 us) with one
// verified-safe delta: gemm LDS stride 40 -> 44 (bank conflicts 1.38M -> ~0,
// measured rounds 10/11).
// geo: thread <-> one (b,i,j) pair; scalar fma dot (every restructure of this
// loop regressed: MFMA x3, dot2, 2-pair — see rounds 6-11 post-mortems).
// gemm: bf16 MFMA, W fp32 column-loaded. Q pre-scaled by 1/8 (exact).
// ---------------------------------------------------------------------------
struct PreArgs {
    const float* A[3];
    const float* W[3];
    const float* bias[3];
    unsigned short* C[3];
    int ns[3], cs[3];
    float scale[3];
    const float* box;
    const int* mask;
    const float* Wg;
    const float* bg;
    unsigned short* lw;   // fp16 [B,H,N,N]
};

__global__ __launch_bounds__(256) void pre_k(PreArgs pa)
{
    // pool: geo  -> WgS f32 [64][8] (2048 B) + bgS f32[8]
    //       gemm -> ABlds u16 [2][64][44] (11264 B)
    __shared__ __align__(16) char pool[11264];
    const int t = threadIdx.x;
    const int r_ = (int)(blockIdx.x % 19), g_ = (int)(blockIdx.x / 19);
    const int l = t & 63, wq = t >> 6;
    const int lrow = l & 15, lgrp = l >> 4;

    if (r_ < 16) {
        // ------------------------- geo -------------------------
        float (*WgS)[8] = (float(*)[8])pool;
        float* bgS = (float*)(pool + 2048);
        if (t < 128) ((float4*)&WgS[0][0])[t] = ((const float4*)pa.Wg)[t];
        if (t < 8) bgS[t] = pa.bg[t];
        __syncthreads();

        const int gb = g_ * 16 + r_;
        const size_t gid = (size_t)gb * 256 + t;
        const int j = (int)(gid & (Nn - 1));
        const int i = (int)((gid >> 9) & (Nn - 1));
        const int b = (int)(gid >> 18);

        const float4 bi = *(const float4*)(pa.box + ((size_t)b * Nn + i) * 4);
        const float4 bj = *(const float4*)(pa.box + ((size_t)b * Nn + j) * 4);
        const float cxi = (bi.x + bi.y) * 0.5f, cyi = (bi.z + bi.w) * 0.5f;
        const float wi = bi.y - bi.x + 1.0f, hi = bi.w - bi.z + 1.0f;
        const float cxj = (bj.x + bj.y) * 0.5f, cyj = (bj.z + bj.w) * 0.5f;
        const float wj = bj.y - bj.x + 1.0f, hj = bj.w - bj.z + 1.0f;

        const float pos0 = __logf(fmaxf(fabsf((cxi - cxj) / wi), 1e-3f));
        const float pos1 = __logf(fmaxf(fabsf((cyi - cyj) / hi), 1e-3f));
        const float pos2 = __logf(wi / wj);
        const float pos3 = __logf(hi / hj);

        const float dimr[8] = {1.0f, 0.421696503f, 0.177827941f, 0.0749894209f,
                               0.0316227766f, 0.0133352143f, 0.00562341325f, 0.00237137371f};

        float acc[8] = {0.f, 0.f, 0.f, 0.f, 0.f, 0.f, 0.f, 0.f};
#pragma unroll 1
        for (int p = 0; p < 4; ++p) {
            const float base = 100.0f * ((p == 0) ? pos0 : (p == 1) ? pos1 : (p == 2) ? pos2 : pos3);
            const int g0 = p << 3;
#pragma unroll
            for (int f = 0; f < 8; ++f) {
                float s, c;
                __sincosf(base * dimr[f], &s, &c);
                const int g = g0 + f;
                const float4 wa = *(const float4*)&WgS[g][0];
                const float4 wb = *(const float4*)&WgS[g][4];
                const float4 ca = *(const float4*)&WgS[g + 32][0];
                const float4 cb = *(const float4*)&WgS[g + 32][4];
                acc[0] = fmaf(s, wa.x, fmaf(c, ca.x, acc[0]));
                acc[1] = fmaf(s, wa.y, fmaf(c, ca.y, acc[1]));
                acc[2] = fmaf(s, wa.z, fmaf(c, ca.z, acc[2]));
                acc[3] = fmaf(s, wa.w, fmaf(c, ca.w, acc[3]));
                acc[4] = fmaf(s, wb.x, fmaf(c, cb.x, acc[4]));
                acc[5] = fmaf(s, wb.y, fmaf(c, cb.y, acc[5]));
                acc[6] = fmaf(s, wb.z, fmaf(c, cb.z, acc[6]));
                acc[7] = fmaf(s, wb.w, fmaf(c, cb.w, acc[7]));
            }
        }

        const int mk = pa.mask[gid];
        const size_t ob_ = (size_t)b * Hh * Nn * Nn + (size_t)i * Nn + j;
#pragma unroll
        for (int hh = 0; hh < 8; ++hh) {
            const float gw = acc[hh] + bgS[hh];
            const float lwv = (mk == 0) ? -60000.0f : __logf(fmaxf(gw, 1e-6f));
            pa.lw[ob_ + (size_t)hh * Nn * Nn] = f2h(lwv);
        }
    } else {
        // ------------------------- qkv gemm -------------------------
        unsigned short (*ABlds)[64][44] = (unsigned short(*)[64][44])pool;
        const int qid = g_ * 3 + (r_ - 16);
        const int z = qid % 3, tid = qid / 3;
        const int col0 = (tid & 7) << 6, row0 = (tid >> 3) << 6;
        const float* __restrict__ A = pa.A[z];
        const float* __restrict__ W = pa.W[z];

        const int lr = t >> 2, lc8 = (t & 3) << 3;
        const int bn = t & 63, bk8 = (t >> 6) << 3;

        f32x4 acc[4];
#pragma unroll
        for (int nf = 0; nf < 4; ++nf) acc[nf] = (f32x4){0.f, 0.f, 0.f, 0.f};

        for (int k0 = 0; k0 < Dd; k0 += 32) {
            const float* Ap = A + (size_t)(row0 + lr) * Dd + k0 + lc8;
            const float4 f1 = *(const float4*)Ap;
            const float4 f2 = *(const float4*)(Ap + 4);
            u16x8 a8;
            a8[0] = f2bf(f1.x); a8[1] = f2bf(f1.y); a8[2] = f2bf(f1.z); a8[3] = f2bf(f1.w);
            a8[4] = f2bf(f2.x); a8[5] = f2bf(f2.y); a8[6] = f2bf(f2.z); a8[7] = f2bf(f2.w);
            u16x8 b8;
#pragma unroll
            for (int jj = 0; jj < 8; ++jj)
                b8[jj] = f2bf(W[(size_t)(k0 + bk8 + jj) * Dd + col0 + bn]);
            __syncthreads();
            *(u16x8*)&ABlds[0][lr][lc8] = a8;
            *(u16x8*)&ABlds[1][bn][bk8] = b8;
            __syncthreads();
            const bf16x8 a = *(const bf16x8*)&ABlds[0][wq * 16 + lrow][lgrp << 3];
#pragma unroll
            for (int nf = 0; nf < 4; ++nf) {
                const bf16x8 bfr = *(const bf16x8*)&ABlds[1][nf * 16 + lrow][lgrp << 3];
                acc[nf] = __builtin_amdgcn_mfma_f32_16x16x32_bf16(a, bfr, acc[nf], 0, 0, 0);
            }
        }

        const float* bias = pa.bias[z];
        const float scl = pa.scale[z];
        const int ns = pa.ns[z], cs = pa.cs[z];
        const int rbase = row0 + wq * 16 + (lgrp << 2);
#pragma unroll
        for (int nf = 0; nf < 4; ++nf) {
            const int colg = col0 + nf * 16 + lrow;
            const float bv = bias[colg];
#pragma unroll
            for (int r = 0; r < 4; ++r) {
                const int rowg = rbase + r;
                const size_t addr = (size_t)(rowg >> 9) * ((size_t)Nn * Dd)
                                  + (size_t)(rowg & (Nn - 1)) * ns + (size_t)colg * cs;
                pa.C[z][addr] = f2bf((acc[nf][r] + bv) * scl);
            }
        }
    }
}

// ---------------------------------------------------------------------------
// Fused flash attention, bf16 MFMA. Block = (b, h, 64 q-rows), 4 waves.
// K/V/logw register-prefetched one chunk ahead; logw LDS-staged fp16.
// Q pre-scaled by 1/8. (unchanged from round 5)
// ---------------------------------------------------------------------------
__global__ __launch_bounds__(256) void attn_k(
    const unsigned short* __restrict__ qb, const unsigned short* __restrict__ kb,
    const unsigned short* __restrict__ vt, const unsigned short* __restrict__ lwh,
    unsigned short* __restrict__ ob)
{
    __shared__ unsigned short Qlds[64][72];
    __shared__ unsigned short Klds[64][72];
    __shared__ unsigned short Vlds[64][72];
    __shared__ unsigned short Plds[4][16][72];
    __shared__ unsigned short LWs[64][72];

    const int t = threadIdx.x;
    const int l = t & 63, wq = t >> 6;
    const int bx = blockIdx.x;
    const int qt = bx & 7, h = (bx >> 3) & 7, b = bx >> 6;
    const int q0 = qt << 6;
    const int sr = t >> 3, sc8 = (t & 7) << 3;
    const int lrow = l & 15, lgrp = l >> 4;
    const int qr0 = t >> 3, c80 = (t & 7) << 3;
    const int qr1 = 32 + (t >> 3), c81 = c80;

    const size_t lwb = ((size_t)(b * Hh + h) * Nn + q0) * Nn;

#pragma unroll
    for (int it = 0; it < 2; ++it) {
        const int r = it * 32 + sr;
        *(u16x8*)&Qlds[r][sc8] =
            *(const u16x8*)(qb + (((size_t)b * Nn + q0 + r) * Hh + h) * DKk + sc8);
    }

    u16x8 kr[2], vr[2], lwr[2];
#pragma unroll
    for (int it = 0; it < 2; ++it) {
        const int r = it * 32 + sr;
        kr[it] = *(const u16x8*)(kb + (((size_t)b * Nn + r) * Hh + h) * DKk + sc8);
        vr[it] = *(const u16x8*)(vt + ((size_t)(b * Hh + h) * DKk + r) * Nn + sc8);
    }
    lwr[0] = *(const u16x8*)(lwh + lwb + (size_t)qr0 * Nn + c80);
    lwr[1] = *(const u16x8*)(lwh + lwb + (size_t)qr1 * Nn + c81);
#pragma unroll
    for (int it = 0; it < 2; ++it) {
        const int r = it * 32 + sr;
        *(u16x8*)&Klds[r][sc8] = kr[it];
        *(u16x8*)&Vlds[r][sc8] = vr[it];
    }
    *(u16x8*)&LWs[qr0][c80] = lwr[0];
    *(u16x8*)&LWs[qr1][c81] = lwr[1];
    __syncthreads();

    bf16x8 qa[2];
    qa[0] = *(const bf16x8*)&Qlds[wq * 16 + lrow][lgrp << 3];
    qa[1] = *(const bf16x8*)&Qlds[wq * 16 + lrow][32 + (lgrp << 3)];

    float m[4], lsum[4];
    f32x4 oacc[4];
#pragma unroll
    for (int r = 0; r < 4; ++r) { m[r] = -1e30f; lsum[r] = 0.f; }
#pragma unroll
    for (int fd = 0; fd < 4; ++fd) oacc[fd] = (f32x4){0.f, 0.f, 0.f, 0.f};

    for (int c = 0; c < 8; ++c) {
        if (c) __syncthreads();
        if (c < 7) {
            const int k1 = (c + 1) << 6;
#pragma unroll
            for (int it = 0; it < 2; ++it) {
                const int r = it * 32 + sr;
                kr[it] = *(const u16x8*)(kb + (((size_t)b * Nn + k1 + r) * Hh + h) * DKk + sc8);
                vr[it] = *(const u16x8*)(vt + ((size_t)(b * Hh + h) * DKk + r) * Nn + k1 + sc8);
            }
            lwr[0] = *(const u16x8*)(lwh + lwb + (size_t)qr0 * Nn + k1 + c80);
            lwr[1] = *(const u16x8*)(lwh + lwb + (size_t)qr1 * Nn + k1 + c81);
        }

        f32x4 sacc[4];
#pragma unroll
        for (int f = 0; f < 4; ++f) sacc[f] = (f32x4){0.f, 0.f, 0.f, 0.f};
#pragma unroll
        for (int ks = 0; ks < 2; ++ks)
#pragma unroll
            for (int f = 0; f < 4; ++f) {
                const bf16x8 kf = *(const bf16x8*)&Klds[f * 16 + lrow][(ks << 5) + (lgrp << 3)];
                sacc[f] = __builtin_amdgcn_mfma_f32_16x16x32_bf16(qa[ks], kf, sacc[f], 0, 0, 0);
            }

        float p[4][4], mx[4];
#pragma unroll
        for (int r = 0; r < 4; ++r) mx[r] = -1e30f;
#pragma unroll
        for (int f = 0; f < 4; ++f) {
#pragma unroll
            for (int r = 0; r < 4; ++r) {
                const float lg = sacc[f][r] + h2f(LWs[wq * 16 + lgrp * 4 + r][f * 16 + lrow]);
                p[f][r] = lg;
                mx[r] = fmaxf(mx[r], lg);
            }
        }
#pragma unroll
        for (int r = 0; r < 4; ++r) {
            float cm = mx[r];
            cm = fmaxf(cm, __shfl_xor(cm, 1));
            cm = fmaxf(cm, __shfl_xor(cm, 2));
            cm = fmaxf(cm, __shfl_xor(cm, 4));
            cm = fmaxf(cm, __shfl_xor(cm, 8));
            const float mn = fmaxf(m[r], cm);
            const float sc = __expf(m[r] - mn);
            m[r] = mn;
            float ps = 0.f;
#pragma unroll
            for (int f = 0; f < 4; ++f) {
                p[f][r] = __expf(p[f][r] - mn);
                ps += p[f][r];
            }
            ps += __shfl_xor(ps, 1);
            ps += __shfl_xor(ps, 2);
            ps += __shfl_xor(ps, 4);
            ps += __shfl_xor(ps, 8);
            lsum[r] = lsum[r] * sc + ps;
#pragma unroll
            for (int fd = 0; fd < 4; ++fd) oacc[fd][r] *= sc;
        }

#pragma unroll
        for (int f = 0; f < 4; ++f)
#pragma unroll
            for (int r = 0; r < 4; ++r)
                Plds[wq][lgrp * 4 + r][f * 16 + lrow] = f2bf(p[f][r]);

#pragma unroll
        for (int ks = 0; ks < 2; ++ks) {
            const bf16x8 pafr = *(const bf16x8*)&Plds[wq][lrow][(ks << 5) + (lgrp << 3)];
#pragma unroll
            for (int fd = 0; fd < 4; ++fd) {
                const bf16x8 vf = *(const bf16x8*)&Vlds[fd * 16 + lrow][(ks << 5) + (lgrp << 3)];
                oacc[fd] = __builtin_amdgcn_mfma_f32_16x16x32_bf16(pafr, vf, oacc[fd], 0, 0, 0);
            }
        }

        if (c < 7) {
            __syncthreads();
#pragma unroll
            for (int it = 0; it < 2; ++it) {
                const int r = it * 32 + sr;
                *(u16x8*)&Klds[r][sc8] = kr[it];
                *(u16x8*)&Vlds[r][sc8] = vr[it];
            }
            *(u16x8*)&LWs[qr0][c80] = lwr[0];
            *(u16x8*)&LWs[qr1][c81] = lwr[1];
        }
    }

#pragma unroll
    for (int r = 0; r < 4; ++r) {
        const float inv = 1.0f / lsum[r];
        const int qrow = q0 + wq * 16 + lgrp * 4 + r;
#pragma unroll
        for (int fd = 0; fd < 4; ++fd) {
            ob[(((size_t)b * Nn + qrow) * Hh + h) * DKk + fd * 16 + lrow] =
                f2bf(oacc[fd][r] * inv);
        }
    }
}

// ---------------------------------------------------------------------------
// Output projection: C[2048,512] fp32 = A(bf16) @ Wo(fp32, column-loaded) + bo
// LDS stride 44.
// ---------------------------------------------------------------------------
__global__ __launch_bounds__(256) void outproj_k(
    const unsigned short* __restrict__ A, const float* __restrict__ W,
    const float* __restrict__ bias, float* __restrict__ C)
{
    __shared__ unsigned short Alds[64][44];
    __shared__ unsigned short Blds[64][44];
    const int t = threadIdx.x;
    const int l = t & 63, wq = t >> 6;
    const int col0 = (int)(blockIdx.x) << 6, row0 = (int)(blockIdx.y) << 6;
    const int lr = t >> 2, lc8 = (t & 3) << 3;
    const int bn = t & 63, bk8 = (t >> 6) << 3;
    const int lrow = l & 15, lgrp = l >> 4;

    f32x4 acc[4];
#pragma unroll
    for (int nf = 0; nf < 4; ++nf) acc[nf] = (f32x4){0.f, 0.f, 0.f, 0.f};

    for (int k0 = 0; k0 < Dd; k0 += 32) {
        const u16x8 a8 = *(const u16x8*)(A + (size_t)(row0 + lr) * Dd + k0 + lc8);
        u16x8 b8;
#pragma unroll
        for (int jj = 0; jj < 8; ++jj)
            b8[jj] = f2bf(W[(size_t)(k0 + bk8 + jj) * Dd + col0 + bn]);
        __syncthreads();
        *(u16x8*)&Alds[lr][lc8] = a8;
        *(u16x8*)&Blds[bn][bk8] = b8;
        __syncthreads();
        const bf16x8 a = *(const bf16x8*)&Alds[wq * 16 + lrow][lgrp << 3];
#pragma unroll
        for (int nf = 0; nf < 4; ++nf) {
            const bf16x8 bfr = *(const bf16x8*)&Blds[nf * 16 + lrow][lgrp << 3];
            acc[nf] = __builtin_amdgcn_mfma_f32_16x16x32_bf16(a, bfr, acc[nf], 0, 0, 0);
        }
    }

    const int rbase = row0 + wq * 16 + (lgrp << 2);
#pragma unroll
    for (int nf = 0; nf < 4; ++nf) {
        const int colg = col0 + nf * 16 + lrow;
        const float bv = bias[colg];
#pragma unroll
        for (int r = 0; r < 4; ++r)
            C[(size_t)(rbase + r) * Dd + colg] = acc[nf][r] + bv;
    }
}

// ---------------------------------------------------------------------------
extern "C" void kernel_launch(void* const* d_in, const int* in_sizes, int n_in,
                              void* d_out, int out_size, void* d_ws, size_t ws_size,
                              hipStream_t stream)
{
    (void)in_sizes; (void)n_in; (void)out_size; (void)ws_size;

    const float* q_in = (const float*)d_in[0];
    const float* k_in = (const float*)d_in[1];
    const float* v_in = (const float*)d_in[2];
    const float* box  = (const float*)d_in[3];
    const int*   mask = (const int*)d_in[4];
    const float* Wq = (const float*)d_in[5];
    const float* bq = (const float*)d_in[6];
    const float* Wk = (const float*)d_in[7];
    const float* bk = (const float*)d_in[8];
    const float* Wv = (const float*)d_in[9];
    const float* bv = (const float*)d_in[10];
    const float* Wo = (const float*)d_in[11];
    const float* bo = (const float*)d_in[12];
    const float* Wg = (const float*)d_in[13];
    const float* bg = (const float*)d_in[14];
    float* out = (float*)d_out;

    char* ws = (char*)d_ws;
    unsigned short* qb  = (unsigned short*)(ws);                 // 2 MB  [b,n,h,d] bf16 (pre-scaled 1/8)
    unsigned short* kb  = (unsigned short*)(ws + (2u << 20));    // 2 MB  [b,n,h,d] bf16
    unsigned short* vt  = (unsigned short*)(ws + (4u << 20));    // 2 MB  [b,h,d,n] bf16
    unsigned short* ob  = (unsigned short*)(ws + (6u << 20));    // 2 MB  [b,n,h,d] bf16
    unsigned short* lwh = (unsigned short*)(ws + (8u << 20));    // 16 MB [b,h,i,j] fp16

    // 1) merged geo + QKV projections, striped 16:3 per 19 blocks (round-5)
    PreArgs pa;
    pa.A[0] = q_in; pa.A[1] = k_in; pa.A[2] = v_in;
    pa.W[0] = Wq;   pa.W[1] = Wk;   pa.W[2] = Wv;
    pa.bias[0] = bq; pa.bias[1] = bk; pa.bias[2] = bv;
    pa.C[0] = qb; pa.C[1] = kb; pa.C[2] = vt;
    pa.ns[0] = Dd; pa.ns[1] = Dd; pa.ns[2] = 1;
    pa.cs[0] = 1;  pa.cs[1] = 1;  pa.cs[2] = Nn;
    pa.scale[0] = 0.125f; pa.scale[1] = 1.0f; pa.scale[2] = 1.0f;
    pa.box = box; pa.mask = mask; pa.Wg = Wg; pa.bg = bg; pa.lw = lwh;
    pre_k<<<dim3(4864), 256, 0, stream>>>(pa);

    // 2) fused attention
    attn_k<<<dim3(Bq * Hh * (Nn / 64)), 256, 0, stream>>>(qb, kb, vt, lwh, ob);

    // 3) output projection
    outproj_k<<<dim3(8, 32), 256, 0, stream>>>(ob, Wo, bo, out);
}

// Round 13
// 81.960 us; speedup vs baseline: 1.4466x; 1.4466x over previous
//
#include <hip/hip_runtime.h>
#include <hip/hip_bf16.h>

#define Bq 4
#define Nn 512
#define Dd 512
#define Hh 8
#define DKk 64

typedef __bf16 bf16x8 __attribute__((ext_vector_type(8)));
typedef float f32x4 __attribute__((ext_vector_type(4)));
typedef unsigned short u16x8 __attribute__((ext_vector_type(8)));

// fp32 -> bf16 RNE (no NaN inputs here)
static __device__ __forceinline__ unsigned short f2bf(float f) {
    unsigned int u = __float_as_uint(f);
    return (unsigned short)((u + 0x7FFFu + ((u >> 16) & 1u)) >> 16);
}
static __device__ __forceinline__ unsigned short f2h(float f) {
    union { _Float16 h; unsigned short u; } cv;
    cv.h = (_Float16)f;
    return cv.u;
}
static __device__ __forceinline__ float h2f(unsigned short us) {
    union { _Float16 h; unsigned short u; } cv;
    cv.u = us;
    return (float)cv.h;
}

// ---------------------------------------------------------------------------
// QKV GEMM, standalone (the long-proven gemm branch). bf16 MFMA, W fp32
// column-loaded, LDS stride 44 (0 conflicts). Q pre-scaled by 1/8 (exact).
// grid (8, 32, 3): z selects Q/K/V.
// ---------------------------------------------------------------------------
struct QkvArgs {
    const float* A[3];
    const float* W[3];
    const float* bias[3];
    unsigned short* C[3];
    int ns[3], cs[3];
    float scale[3];
};

__global__ __launch_bounds__(256) void qkv_k(QkvArgs qa)
{
    __shared__ unsigned short Alds[64][44];
    __shared__ unsigned short Blds[64][44];
    const int t = threadIdx.x;
    const int l = t & 63, wq = t >> 6;
    const int lrow = l & 15, lgrp = l >> 4;
    const int z = (int)blockIdx.z;
    const int col0 = (int)blockIdx.x << 6, row0 = (int)blockIdx.y << 6;
    const float* __restrict__ A = qa.A[z];
    const float* __restrict__ W = qa.W[z];

    const int lr = t >> 2, lc8 = (t & 3) << 3;
    const int bn = t & 63, bk8 = (t >> 6) << 3;

    f32x4 acc[4];
#pragma unroll
    for (int nf = 0; nf < 4; ++nf) acc[nf] = (f32x4){0.f, 0.f, 0.f, 0.f};

    for (int k0 = 0; k0 < Dd; k0 += 32) {
        const float* Ap = A + (size_t)(row0 + lr) * Dd + k0 + lc8;
        const float4 f1 = *(const float4*)Ap;
        const float4 f2 = *(const float4*)(Ap + 4);
        u16x8 a8;
        a8[0] = f2bf(f1.x); a8[1] = f2bf(f1.y); a8[2] = f2bf(f1.z); a8[3] = f2bf(f1.w);
        a8[4] = f2bf(f2.x); a8[5] = f2bf(f2.y); a8[6] = f2bf(f2.z); a8[7] = f2bf(f2.w);
        u16x8 b8;
#pragma unroll
        for (int jj = 0; jj < 8; ++jj)
            b8[jj] = f2bf(W[(size_t)(k0 + bk8 + jj) * Dd + col0 + bn]);
        __syncthreads();
        *(u16x8*)&Alds[lr][lc8] = a8;
        *(u16x8*)&Blds[bn][bk8] = b8;
        __syncthreads();
        const bf16x8 a = *(const bf16x8*)&Alds[wq * 16 + lrow][lgrp << 3];
#pragma unroll
        for (int nf = 0; nf < 4; ++nf) {
            const bf16x8 bfr = *(const bf16x8*)&Blds[nf * 16 + lrow][lgrp << 3];
            acc[nf] = __builtin_amdgcn_mfma_f32_16x16x32_bf16(a, bfr, acc[nf], 0, 0, 0);
        }
    }

    const float* bias = qa.bias[z];
    const float scl = qa.scale[z];
    const int ns = qa.ns[z], cs = qa.cs[z];
    const int rbase = row0 + wq * 16 + (lgrp << 2);
#pragma unroll
    for (int nf = 0; nf < 4; ++nf) {
        const int colg = col0 + nf * 16 + lrow;
        const float bv = bias[colg];
#pragma unroll
        for (int r = 0; r < 4; ++r) {
            const int rowg = rbase + r;
            const size_t addr = (size_t)(rowg >> 9) * ((size_t)Nn * Dd)
                              + (size_t)(rowg & (Nn - 1)) * ns + (size_t)colg * cs;
            qa.C[z][addr] = f2bf((acc[nf][r] + bv) * scl);
        }
    }
}

// ---------------------------------------------------------------------------
// geo variant A (b in {0,1}): EXACT r5/r12 interior — LDS-staged weights,
// scalar fma dot. Same-session baseline for the A/B.
// ---------------------------------------------------------------------------
__global__ __launch_bounds__(256) void geoA_k(
    const float* __restrict__ box, const int* __restrict__ mask,
    const float* __restrict__ Wg, const float* __restrict__ bg,
    unsigned short* __restrict__ lw)
{
    __shared__ float WgS[64][8];
    __shared__ float bgS[8];
    const int t = threadIdx.x;
    if (t < 128) ((float4*)&WgS[0][0])[t] = ((const float4*)Wg)[t];
    if (t < 8) bgS[t] = bg[t];
    __syncthreads();

    const size_t gid = (size_t)blockIdx.x * 256 + t;      // b in {0,1}
    const int j = (int)(gid & (Nn - 1));
    const int i = (int)((gid >> 9) & (Nn - 1));
    const int b = (int)(gid >> 18);

    const float4 bi = *(const float4*)(box + ((size_t)b * Nn + i) * 4);
    const float4 bj = *(const float4*)(box + ((size_t)b * Nn + j) * 4);
    const float cxi = (bi.x + bi.y) * 0.5f, cyi = (bi.z + bi.w) * 0.5f;
    const float wi = bi.y - bi.x + 1.0f, hi = bi.w - bi.z + 1.0f;
    const float cxj = (bj.x + bj.y) * 0.5f, cyj = (bj.z + bj.w) * 0.5f;
    const float wj = bj.y - bj.x + 1.0f, hj = bj.w - bj.z + 1.0f;

    const float pos0 = __logf(fmaxf(fabsf((cxi - cxj) / wi), 1e-3f));
    const float pos1 = __logf(fmaxf(fabsf((cyi - cyj) / hi), 1e-3f));
    const float pos2 = __logf(wi / wj);
    const float pos3 = __logf(hi / hj);

    const float dimr[8] = {1.0f, 0.421696503f, 0.177827941f, 0.0749894209f,
                           0.0316227766f, 0.0133352143f, 0.00562341325f, 0.00237137371f};

    float acc[8] = {0.f, 0.f, 0.f, 0.f, 0.f, 0.f, 0.f, 0.f};
#pragma unroll 1
    for (int p = 0; p < 4; ++p) {
        const float base = 100.0f * ((p == 0) ? pos0 : (p == 1) ? pos1 : (p == 2) ? pos2 : pos3);
        const int g0 = p << 3;
#pragma unroll
        for (int f = 0; f < 8; ++f) {
            float s, c;
            __sincosf(base * dimr[f], &s, &c);
            const int g = g0 + f;
            const float4 wa = *(const float4*)&WgS[g][0];
            const float4 wb = *(const float4*)&WgS[g][4];
            const float4 ca = *(const float4*)&WgS[g + 32][0];
            const float4 cb = *(const float4*)&WgS[g + 32][4];
            acc[0] = fmaf(s, wa.x, fmaf(c, ca.x, acc[0]));
            acc[1] = fmaf(s, wa.y, fmaf(c, ca.y, acc[1]));
            acc[2] = fmaf(s, wa.z, fmaf(c, ca.z, acc[2]));
            acc[3] = fmaf(s, wa.w, fmaf(c, ca.w, acc[3]));
            acc[4] = fmaf(s, wb.x, fmaf(c, cb.x, acc[4]));
            acc[5] = fmaf(s, wb.y, fmaf(c, cb.y, acc[5]));
            acc[6] = fmaf(s, wb.z, fmaf(c, cb.z, acc[6]));
            acc[7] = fmaf(s, wb.w, fmaf(c, cb.w, acc[7]));
        }
    }

    const int mk = mask[gid];
    const size_t ob_ = (size_t)b * Hh * Nn * Nn + (size_t)i * Nn + j;
#pragma unroll
    for (int hh = 0; hh < 8; ++hh) {
        const float gw = acc[hh] + bgS[hh];
        const float lwv = (mk == 0) ? -60000.0f : __logf(fmaxf(gw, 1e-6f));
        lw[ob_ + (size_t)hh * Nn * Nn] = f2h(lwv);
    }
}

// ---------------------------------------------------------------------------
// geo variant B (b in {2,3}): ZERO LDS. All 32 sincos computed first into
// registers (compile-time indices), then 64x8 dot with Wg read via
// wave-uniform global loads (compiler scalarizes to s_load through K$ —
// per-wave, not per-lane). Tests the "geo is LDS-read-stall bound" theory.
// ---------------------------------------------------------------------------
__global__ __launch_bounds__(256) void geoB_k(
    const float* __restrict__ box, const int* __restrict__ mask,
    const float* __restrict__ Wg, const float* __restrict__ bg,
    unsigned short* __restrict__ lw)
{
    const int t = threadIdx.x;
    const size_t gid = ((size_t)1 << 19) + (size_t)blockIdx.x * 256 + t;   // b in {2,3}
    const int j = (int)(gid & (Nn - 1));
    const int i = (int)((gid >> 9) & (Nn - 1));
    const int b = (int)(gid >> 18);

    const float4 bi = *(const float4*)(box + ((size_t)b * Nn + i) * 4);
    const float4 bj = *(const float4*)(box + ((size_t)b * Nn + j) * 4);
    const float cxi = (bi.x + bi.y) * 0.5f, cyi = (bi.z + bi.w) * 0.5f;
    const float wi = bi.y - bi.x + 1.0f, hi = bi.w - bi.z + 1.0f;
    const float cxj = (bj.x + bj.y) * 0.5f, cyj = (bj.z + bj.w) * 0.5f;
    const float wj = bj.y - bj.x + 1.0f, hj = bj.w - bj.z + 1.0f;

    const float bases[4] = {
        100.0f * __logf(fmaxf(fabsf((cxi - cxj) / wi), 1e-3f)),
        100.0f * __logf(fmaxf(fabsf((cyi - cyj) / hi), 1e-3f)),
        100.0f * __logf(wi / wj),
        100.0f * __logf(hi / hj)
    };

    const float dimr[8] = {1.0f, 0.421696503f, 0.177827941f, 0.0749894209f,
                           0.0316227766f, 0.0133352143f, 0.00562341325f, 0.00237137371f};

    // emb[k]: sin at k<32, cos at k>=32 — all indices compile-time (rule #20)
    float emb[64];
#pragma unroll
    for (int p = 0; p < 4; ++p) {
#pragma unroll
        for (int f = 0; f < 8; ++f) {
            float s, c;
            __sincosf(bases[p] * dimr[f], &s, &c);
            emb[(p << 3) + f] = s;
            emb[32 + (p << 3) + f] = c;
        }
    }

    const int mk = mask[gid];
    const size_t ob_ = (size_t)b * Hh * Nn * Nn + (size_t)i * Nn + j;
#pragma unroll
    for (int hh = 0; hh < 8; ++hh) {
        float a = bg[hh];
#pragma unroll
        for (int k = 0; k < 64; ++k)
            a = fmaf(emb[k], Wg[(size_t)k * Hh + hh], a);
        const float lwv = (mk == 0) ? -60000.0f : __logf(fmaxf(a, 1e-6f));
        lw[ob_ + (size_t)hh * Nn * Nn] = f2h(lwv);
    }
}

// ---------------------------------------------------------------------------
// Fused flash attention, bf16 MFMA. Block = (b, h, 64 q-rows), 4 waves.
// K/V/logw register-prefetched one chunk ahead; logw LDS-staged fp16.
// Q pre-scaled by 1/8. (unchanged)
// ---------------------------------------------------------------------------
__global__ __launch_bounds__(256) void attn_k(
    const unsigned short* __restrict__ qb, const unsigned short* __restrict__ kb,
    const unsigned short* __restrict__ vt, const unsigned short* __restrict__ lwh,
    unsigned short* __restrict__ ob)
{
    __shared__ unsigned short Qlds[64][72];
    __shared__ unsigned short Klds[64][72];
    __shared__ unsigned short Vlds[64][72];
    __shared__ unsigned short Plds[4][16][72];
    __shared__ unsigned short LWs[64][72];

    const int t = threadIdx.x;
    const int l = t & 63, wq = t >> 6;
    const int bx = blockIdx.x;
    const int qt = bx & 7, h = (bx >> 3) & 7, b = bx >> 6;
    const int q0 = qt << 6;
    const int sr = t >> 3, sc8 = (t & 7) << 3;
    const int lrow = l & 15, lgrp = l >> 4;
    const int qr0 = t >> 3, c80 = (t & 7) << 3;
    const int qr1 = 32 + (t >> 3), c81 = c80;

    const size_t lwb = ((size_t)(b * Hh + h) * Nn + q0) * Nn;

#pragma unroll
    for (int it = 0; it < 2; ++it) {
        const int r = it * 32 + sr;
        *(u16x8*)&Qlds[r][sc8] =
            *(const u16x8*)(qb + (((size_t)b * Nn + q0 + r) * Hh + h) * DKk + sc8);
    }

    u16x8 kr[2], vr[2], lwr[2];
#pragma unroll
    for (int it = 0; it < 2; ++it) {
        const int r = it * 32 + sr;
        kr[it] = *(const u16x8*)(kb + (((size_t)b * Nn + r) * Hh + h) * DKk + sc8);
        vr[it] = *(const u16x8*)(vt + ((size_t)(b * Hh + h) * DKk + r) * Nn + sc8);
    }
    lwr[0] = *(const u16x8*)(lwh + lwb + (size_t)qr0 * Nn + c80);
    lwr[1] = *(const u16x8*)(lwh + lwb + (size_t)qr1 * Nn + c81);
#pragma unroll
    for (int it = 0; it < 2; ++it) {
        const int r = it * 32 + sr;
        *(u16x8*)&Klds[r][sc8] = kr[it];
        *(u16x8*)&Vlds[r][sc8] = vr[it];
    }
    *(u16x8*)&LWs[qr0][c80] = lwr[0];
    *(u16x8*)&LWs[qr1][c81] = lwr[1];
    __syncthreads();

    bf16x8 qa[2];
    qa[0] = *(const bf16x8*)&Qlds[wq * 16 + lrow][lgrp << 3];
    qa[1] = *(const bf16x8*)&Qlds[wq * 16 + lrow][32 + (lgrp << 3)];

    float m[4], lsum[4];
    f32x4 oacc[4];
#pragma unroll
    for (int r = 0; r < 4; ++r) { m[r] = -1e30f; lsum[r] = 0.f; }
#pragma unroll
    for (int fd = 0; fd < 4; ++fd) oacc[fd] = (f32x4){0.f, 0.f, 0.f, 0.f};

    for (int c = 0; c < 8; ++c) {
        if (c) __syncthreads();
        if (c < 7) {
            const int k1 = (c + 1) << 6;
#pragma unroll
            for (int it = 0; it < 2; ++it) {
                const int r = it * 32 + sr;
                kr[it] = *(const u16x8*)(kb + (((size_t)b * Nn + k1 + r) * Hh + h) * DKk + sc8);
                vr[it] = *(const u16x8*)(vt + ((size_t)(b * Hh + h) * DKk + r) * Nn + k1 + sc8);
            }
            lwr[0] = *(const u16x8*)(lwh + lwb + (size_t)qr0 * Nn + k1 + c80);
            lwr[1] = *(const u16x8*)(lwh + lwb + (size_t)qr1 * Nn + k1 + c81);
        }

        f32x4 sacc[4];
#pragma unroll
        for (int f = 0; f < 4; ++f) sacc[f] = (f32x4){0.f, 0.f, 0.f, 0.f};
#pragma unroll
        for (int ks = 0; ks < 2; ++ks)
#pragma unroll
            for (int f = 0; f < 4; ++f) {
                const bf16x8 kf = *(const bf16x8*)&Klds[f * 16 + lrow][(ks << 5) + (lgrp << 3)];
                sacc[f] = __builtin_amdgcn_mfma_f32_16x16x32_bf16(qa[ks], kf, sacc[f], 0, 0, 0);
            }

        float p[4][4], mx[4];
#pragma unroll
        for (int r = 0; r < 4; ++r) mx[r] = -1e30f;
#pragma unroll
        for (int f = 0; f < 4; ++f) {
#pragma unroll
            for (int r = 0; r < 4; ++r) {
                const float lg = sacc[f][r] + h2f(LWs[wq * 16 + lgrp * 4 + r][f * 16 + lrow]);
                p[f][r] = lg;
                mx[r] = fmaxf(mx[r], lg);
            }
        }
#pragma unroll
        for (int r = 0; r < 4; ++r) {
            float cm = mx[r];
            cm = fmaxf(cm, __shfl_xor(cm, 1));
            cm = fmaxf(cm, __shfl_xor(cm, 2));
            cm = fmaxf(cm, __shfl_xor(cm, 4));
            cm = fmaxf(cm, __shfl_xor(cm, 8));
            const float mn = fmaxf(m[r], cm);
            const float sc = __expf(m[r] - mn);
            m[r] = mn;
            float ps = 0.f;
#pragma unroll
            for (int f = 0; f < 4; ++f) {
                p[f][r] = __expf(p[f][r] - mn);
                ps += p[f][r];
            }
            ps += __shfl_xor(ps, 1);
            ps += __shfl_xor(ps, 2);
            ps += __shfl_xor(ps, 4);
            ps += __shfl_xor(ps, 8);
            lsum[r] = lsum[r] * sc + ps;
#pragma unroll
            for (int fd = 0; fd < 4; ++fd) oacc[fd][r] *= sc;
        }

#pragma unroll
        for (int f = 0; f < 4; ++f)
#pragma unroll
            for (int r = 0; r < 4; ++r)
                Plds[wq][lgrp * 4 + r][f * 16 + lrow] = f2bf(p[f][r]);

#pragma unroll
        for (int ks = 0; ks < 2; ++ks) {
            const bf16x8 pafr = *(const bf16x8*)&Plds[wq][lrow][(ks << 5) + (lgrp << 3)];
#pragma unroll
            for (int fd = 0; fd < 4; ++fd) {
                const bf16x8 vf = *(const bf16x8*)&Vlds[fd * 16 + lrow][(ks << 5) + (lgrp << 3)];
                oacc[fd] = __builtin_amdgcn_mfma_f32_16x16x32_bf16(pafr, vf, oacc[fd], 0, 0, 0);
            }
        }

        if (c < 7) {
            __syncthreads();
#pragma unroll
            for (int it = 0; it < 2; ++it) {
                const int r = it * 32 + sr;
                *(u16x8*)&Klds[r][sc8] = kr[it];
                *(u16x8*)&Vlds[r][sc8] = vr[it];
            }
            *(u16x8*)&LWs[qr0][c80] = lwr[0];
            *(u16x8*)&LWs[qr1][c81] = lwr[1];
        }
    }

#pragma unroll
    for (int r = 0; r < 4; ++r) {
        const float inv = 1.0f / lsum[r];
        const int qrow = q0 + wq * 16 + lgrp * 4 + r;
#pragma unroll
        for (int fd = 0; fd < 4; ++fd) {
            ob[(((size_t)b * Nn + qrow) * Hh + h) * DKk + fd * 16 + lrow] =
                f2bf(oacc[fd][r] * inv);
        }
    }
}

// ---------------------------------------------------------------------------
// Output projection: C[2048,512] fp32 = A(bf16) @ Wo(fp32, column-loaded) + bo
// LDS stride 44.
// ---------------------------------------------------------------------------
__global__ __launch_bounds__(256) void outproj_k(
    const unsigned short* __restrict__ A, const float* __restrict__ W,
    const float* __restrict__ bias, float* __restrict__ C)
{
    __shared__ unsigned short Alds[64][44];
    __shared__ unsigned short Blds[64][44];
    const int t = threadIdx.x;
    const int l = t & 63, wq = t >> 6;
    const int col0 = (int)(blockIdx.x) << 6, row0 = (int)(blockIdx.y) << 6;
    const int lr = t >> 2, lc8 = (t & 3) << 3;
    const int bn = t & 63, bk8 = (t >> 6) << 3;
    const int lrow = l & 15, lgrp = l >> 4;

    f32x4 acc[4];
#pragma unroll
    for (int nf = 0; nf < 4; ++nf) acc[nf] = (f32x4){0.f, 0.f, 0.f, 0.f};

    for (int k0 = 0; k0 < Dd; k0 += 32) {
        const u16x8 a8 = *(const u16x8*)(A + (size_t)(row0 + lr) * Dd + k0 + lc8);
        u16x8 b8;
#pragma unroll
        for (int jj = 0; jj < 8; ++jj)
            b8[jj] = f2bf(W[(size_t)(k0 + bk8 + jj) * Dd + col0 + bn]);
        __syncthreads();
        *(u16x8*)&Alds[lr][lc8] = a8;
        *(u16x8*)&Blds[bn][bk8] = b8;
        __syncthreads();
        const bf16x8 a = *(const bf16x8*)&Alds[wq * 16 + lrow][lgrp << 3];
#pragma unroll
        for (int nf = 0; nf < 4; ++nf) {
            const bf16x8 bfr = *(const bf16x8*)&Blds[nf * 16 + lrow][lgrp << 3];
            acc[nf] = __builtin_amdgcn_mfma_f32_16x16x32_bf16(a, bfr, acc[nf], 0, 0, 0);
        }
    }

    const int rbase = row0 + wq * 16 + (lgrp << 2);
#pragma unroll
    for (int nf = 0; nf < 4; ++nf) {
        const int colg = col0 + nf * 16 + lrow;
        const float bv = bias[colg];
#pragma unroll
        for (int r = 0; r < 4; ++r)
            C[(size_t)(rbase + r) * Dd + colg] = acc[nf][r] + bv;
    }
}

// ---------------------------------------------------------------------------
extern "C" void kernel_launch(void* const* d_in, const int* in_sizes, int n_in,
                              void* d_out, int out_size, void* d_ws, size_t ws_size,
                              hipStream_t stream)
{
    (void)in_sizes; (void)n_in; (void)out_size; (void)ws_size;

    const float* q_in = (const float*)d_in[0];
    const float* k_in = (const float*)d_in[1];
    const float* v_in = (const float*)d_in[2];
    const float* box  = (const float*)d_in[3];
    const int*   mask = (const int*)d_in[4];
    const float* Wq = (const float*)d_in[5];
    const float* bq = (const float*)d_in[6];
    const float* Wk = (const float*)d_in[7];
    const float* bk = (const float*)d_in[8];
    const float* Wv = (const float*)d_in[9];
    const float* bv = (const float*)d_in[10];
    const float* Wo = (const float*)d_in[11];
    const float* bo = (const float*)d_in[12];
    const float* Wg = (const float*)d_in[13];
    const float* bg = (const float*)d_in[14];
    float* out = (float*)d_out;

    char* ws = (char*)d_ws;
    unsigned short* qb  = (unsigned short*)(ws);                 // 2 MB  [b,n,h,d] bf16 (pre-scaled 1/8)
    unsigned short* kb  = (unsigned short*)(ws + (2u << 20));    // 2 MB  [b,n,h,d] bf16
    unsigned short* vt  = (unsigned short*)(ws + (4u << 20));    // 2 MB  [b,h,d,n] bf16
    unsigned short* ob  = (unsigned short*)(ws + (6u << 20));    // 2 MB  [b,n,h,d] bf16
    unsigned short* lwh = (unsigned short*)(ws + (8u << 20));    // 16 MB [b,h,i,j] fp16

    // 1) QKV projections (standalone)
    QkvArgs qa;
    qa.A[0] = q_in; qa.A[1] = k_in; qa.A[2] = v_in;
    qa.W[0] = Wq;   qa.W[1] = Wk;   qa.W[2] = Wv;
    qa.bias[0] = bq; qa.bias[1] = bk; qa.bias[2] = bv;
    qa.C[0] = qb; qa.C[1] = kb; qa.C[2] = vt;
    qa.ns[0] = Dd; qa.ns[1] = Dd; qa.ns[2] = 1;
    qa.cs[0] = 1;  qa.cs[1] = 1;  qa.cs[2] = Nn;
    qa.scale[0] = 0.125f; qa.scale[1] = 1.0f; qa.scale[2] = 1.0f;
    qkv_k<<<dim3(8, 32, 3), 256, 0, stream>>>(qa);

    // 2) geo A/B split (same-session comparison): A = b{0,1}, B = b{2,3}
    geoA_k<<<dim3(2048), 256, 0, stream>>>(box, mask, Wg, bg, lwh);
    geoB_k<<<dim3(2048), 256, 0, stream>>>(box, mask, Wg, bg, lwh);

    // 3) fused attention
    attn_k<<<dim3(Bq * Hh * (Nn / 64)), 256, 0, stream>>>(qb, kb, vt, lwh, ob);

    // 4) output projection
    outproj_k<<<dim3(8, 32), 256, 0, stream>>>(ob, Wo, bo, out);
}